// Round 9
// baseline (854.896 us; speedup 1.0000x reference)
//
#include <hip/hip_runtime.h>
#include <cstdint>

#define PARTITIONABLE 1

static constexpr int Bsz = 4, Lsz = 1024, Dsz = 1024, Hn = 16, HDsz = 64;
static constexpr size_t ELEMS = (size_t)Bsz * Lsz * Dsz;     // 4194304
static constexpr uint32_t HALF_N = (uint32_t)(ELEMS / 2);
static constexpr float SCALE = 0.125f;
static constexpr float P_NOISE = 0.05f;
static constexpr float S_NOISE = 0.1f;
static constexpr size_t MBy = 1024 * 1024;

typedef unsigned short u16;
typedef uint64_t u64;
typedef __attribute__((ext_vector_type(8))) short short8v;
typedef __attribute__((ext_vector_type(4))) float floatx4;
typedef __attribute__((ext_vector_type(4))) unsigned int uint4v;

// ---- async global->LDS, 16B per lane. LDS dest wave-uniform base + lane*16.
__device__ __forceinline__ void gload16(const u16* g, u16* l) {
  __builtin_amdgcn_global_load_lds(
      (const __attribute__((address_space(1))) void*)(g),
      (__attribute__((address_space(3))) void*)(l), 16, 0, 0);
}

// ---------------- threefry2x32 (exact JAX semantics) ----------------
__host__ __device__ __forceinline__ void tf2x32(uint32_t k0, uint32_t k1,
                                                uint32_t x0, uint32_t x1,
                                                uint32_t& o0, uint32_t& o1) {
  uint32_t ks2 = k0 ^ k1 ^ 0x1BD11BDAu;
  x0 += k0; x1 += k1;
#define TFR(r) { x0 += x1; x1 = (x1 << (r)) | (x1 >> (32 - (r))); x1 ^= x0; }
  TFR(13) TFR(15) TFR(26) TFR(6)
  x0 += k1; x1 += ks2 + 1u;
  TFR(17) TFR(29) TFR(16) TFR(24)
  x0 += ks2; x1 += k0 + 2u;
  TFR(13) TFR(15) TFR(26) TFR(6)
  x0 += k0; x1 += k1 + 3u;
  TFR(17) TFR(29) TFR(16) TFR(24)
  x0 += k1; x1 += ks2 + 4u;
  TFR(13) TFR(15) TFR(26) TFR(6)
  x0 += ks2; x1 += k0 + 5u;
#undef TFR
  o0 = x0; o1 = x1;
}

struct KeySet { uint32_t k[5][2]; };
struct AllKeys { KeySet t[3]; };

__device__ __forceinline__ uint32_t draw_bits(uint32_t k0, uint32_t k1, uint32_t idx) {
#if PARTITIONABLE
  uint32_t o0, o1; tf2x32(k0, k1, 0u, idx, o0, o1);
  return o0 ^ o1;
#else
  uint32_t o0, o1;
  if (idx < HALF_N) { tf2x32(k0, k1, idx, idx + HALF_N, o0, o1); return o0; }
  tf2x32(k0, k1, idx - HALF_N, idx, o0, o1); return o1;
#endif
}

__device__ __forceinline__ float unif01(uint32_t bits) {
  return __uint_as_float((bits >> 9) | 0x3f800000u) - 1.0f;
}

__device__ __forceinline__ float normal_from_bits(uint32_t bits) {
  const float LO = -0.99999994f;
  float f = unif01(bits);
  float x = fmaxf(LO, f * 2.0f + LO);
  float w = -log1pf(-x * x);
  float p;
  if (w < 5.0f) {
    w = w - 2.5f;
    p = 2.81022636e-08f;
    p = fmaf(p, w, 3.43273939e-07f);
    p = fmaf(p, w, -3.5233877e-06f);
    p = fmaf(p, w, -4.39150654e-06f);
    p = fmaf(p, w, 0.00021858087f);
    p = fmaf(p, w, -0.00125372503f);
    p = fmaf(p, w, -0.00417768164f);
    p = fmaf(p, w, 0.246640727f);
    p = fmaf(p, w, 1.50140941f);
  } else {
    w = sqrtf(w) - 3.0f;
    p = -0.000200214257f;
    p = fmaf(p, w, 0.000100950558f);
    p = fmaf(p, w, 0.00134934322f);
    p = fmaf(p, w, -0.00367342844f);
    p = fmaf(p, w, 0.00573950773f);
    p = fmaf(p, w, -0.0076224613f);
    p = fmaf(p, w, 0.00943887047f);
    p = fmaf(p, w, 1.00167406f);
    p = fmaf(p, w, 2.83297682f);
  }
  return 1.41421356f * (p * x);
}

// ---------------- f32 -> (hi,lo) bf16 split ----------------
__device__ __forceinline__ uint32_t bf16_rn(float f) {
  uint32_t u = __float_as_uint(f);
  return (u + 0x7FFFu + ((u >> 16) & 1u)) >> 16;
}
__device__ __forceinline__ float bf2f(uint32_t h) { return __uint_as_float(h << 16); }
__device__ __forceinline__ void cvt_split(float4 v, u64& hi, u64& lo) {
  uint32_t h0 = bf16_rn(v.x), h1 = bf16_rn(v.y), h2 = bf16_rn(v.z), h3 = bf16_rn(v.w);
  float r0 = v.x - bf2f(h0), r1 = v.y - bf2f(h1), r2 = v.z - bf2f(h2), r3 = v.w - bf2f(h3);
  uint32_t l0 = bf16_rn(r0), l1 = bf16_rn(r1), l2 = bf16_rn(r2), l3 = bf16_rn(r3);
  hi = (u64)h0 | ((u64)h1 << 16) | ((u64)h2 << 32) | ((u64)h3 << 48);
  lo = (u64)l0 | ((u64)l1 << 16) | ((u64)l2 << 32) | ((u64)l3 << 48);
}

// ---------------- BK=32 MFMA step on the fragment-packed LDS tile ------------
__device__ __forceinline__ void mfma_step(const u16* Ahs, const u16* Als,
                                          const u16* Bhs, const u16* Bls,
                                          int pr, int wm, int wn, floatx4 acc[4][4]) {
  short8v aH[4], aL[4], bH[4], bL[4];
#pragma unroll
  for (int t = 0; t < 4; ++t) {
    const int ia = ((wm * 4 + t) * 64 + pr) * 8;
    aH[t] = *(const short8v*)&Ahs[ia]; aL[t] = *(const short8v*)&Als[ia];
    const int ib = ((wn * 4 + t) * 64 + pr) * 8;
    bH[t] = *(const short8v*)&Bhs[ib]; bL[t] = *(const short8v*)&Bls[ib];
  }
#pragma unroll
  for (int mt = 0; mt < 4; ++mt)
#pragma unroll
    for (int nt = 0; nt < 4; ++nt) {
      acc[mt][nt] = __builtin_amdgcn_mfma_f32_16x16x32_bf16(aH[mt], bH[nt], acc[mt][nt], 0, 0, 0);
      acc[mt][nt] = __builtin_amdgcn_mfma_f32_16x16x32_bf16(aH[mt], bL[nt], acc[mt][nt], 0, 0, 0);
      acc[mt][nt] = __builtin_amdgcn_mfma_f32_16x16x32_bf16(aL[mt], bH[nt], acc[mt][nt], 0, 0, 0);
    }
}

// ---------------- batched elementwise splitter: f32 -> hi/lo bf16 ------------
struct SJob { const float* src; u16* dh; u16* dl; int n4; };
struct SJobs { SJob j[8]; };

__global__ __launch_bounds__(256) void split8_kernel(SJobs js) {
  const SJob J = js.j[blockIdx.y];
  int i = blockIdx.x * 256 + (int)threadIdx.x;
  if (i >= J.n4) return;
  float4 v = ((const float4*)J.src)[i];
  u64 h, l; cvt_split(v, h, l);
  ((u64*)J.dh)[i] = h; ((u64*)J.dl)[i] = l;
}

// ---------------- GEMM: Y = A @ W^T + bias; all operands pre-split -----------
// Double-buffered BK=32, 64 KB LDS, 2 blocks/CU (T3-minimum pipeline).
// MODE 0: split-u16 out.  MODE 1: f32 out.
struct GJob { const u16* Ah; const u16* Al; const u16* Wh; const u16* Wl;
              const float* bias; float* Yf; u16* Yh; u16* Yl; };
struct GJobs { GJob j[6]; };

template<int MODE>
__global__ __launch_bounds__(256, 2) void gemm_kernel(GJobs jobs) {
  const GJob J = jobs.j[blockIdx.z];
  const int n0 = blockIdx.x * 128, m0 = blockIdx.y * 128;
  __shared__ u16 Ahs[2][4096], Als[2][4096], Bhs[2][4096], Bls[2][4096];
  const int tid = (int)threadIdx.x, w = tid >> 6, l = tid & 63;
  const int wm = w >> 1, wn = w & 1;
  const int qA = (l ^ (l >> 4)) & 15, colA = (l >> 4) * 8;
  const int pr = (l ^ (l >> 4)) & 63;
  const int t0 = w * 2, t1 = w * 2 + 1;

  const u16* ahp = J.Ah + (size_t)(m0 + qA) * Dsz + colA;
  const u16* alp = J.Al + (size_t)(m0 + qA) * Dsz + colA;
  const u16* whp = J.Wh + (size_t)(n0 + qA) * Dsz + colA;
  const u16* wlp = J.Wl + (size_t)(n0 + qA) * Dsz + colA;

  floatx4 acc[4][4];
#pragma unroll
  for (int i = 0; i < 4; ++i)
#pragma unroll
    for (int j = 0; j < 4; ++j) acc[i][j] = (floatx4){0.f, 0.f, 0.f, 0.f};

#define STG(bufi, K0V) { \
    const size_t g0 = (size_t)(t0 * 16) * Dsz + (K0V); \
    const size_t g1 = (size_t)(t1 * 16) * Dsz + (K0V); \
    gload16(ahp + g0, &Ahs[bufi][t0 * 512]); gload16(ahp + g1, &Ahs[bufi][t1 * 512]); \
    gload16(alp + g0, &Als[bufi][t0 * 512]); gload16(alp + g1, &Als[bufi][t1 * 512]); \
    gload16(whp + g0, &Bhs[bufi][t0 * 512]); gload16(whp + g1, &Bhs[bufi][t1 * 512]); \
    gload16(wlp + g0, &Bls[bufi][t0 * 512]); gload16(wlp + g1, &Bls[bufi][t1 * 512]); }

  STG(0, 0)
  __syncthreads();
  for (int kt = 0; kt < 32; kt += 2) {
    if (kt + 1 < 32) STG(1, (size_t)(kt + 1) * 32)
    mfma_step(Ahs[0], Als[0], Bhs[0], Bls[0], pr, wm, wn, acc);
    __syncthreads();
    if (kt + 2 < 32) STG(0, (size_t)(kt + 2) * 32)
    mfma_step(Ahs[1], Als[1], Bhs[1], Bls[1], pr, wm, wn, acc);
    __syncthreads();
  }
#undef STG

  const int colLane = l & 15, rquad = l >> 4;
#pragma unroll
  for (int nt = 0; nt < 4; ++nt) {
    const int col = n0 + wn * 64 + nt * 16 + colLane;
    const float bv = J.bias[col];
#pragma unroll
    for (int mt = 0; mt < 4; ++mt) {
      const int r0 = m0 + wm * 64 + mt * 16 + rquad * 4;
#pragma unroll
      for (int j2 = 0; j2 < 4; ++j2) {
        float v = acc[mt][nt][j2] + bv;
        if (MODE == 1) {
          J.Yf[(size_t)(r0 + j2) * Dsz + col] = v;
        } else {
          const uint32_t hi = bf16_rn(v);
          const uint32_t lo = bf16_rn(v - bf2f(hi));
          J.Yh[(size_t)(r0 + j2) * Dsz + col] = (u16)hi;
          J.Yl[(size_t)(r0 + j2) * Dsz + col] = (u16)lo;
        }
      }
    }
  }
}

// ---------------- noise + diag(ent), in place on split q/k/v ----------------
__global__ __launch_bounds__(256) void noise_kernel(
    u16* __restrict__ qhr, u16* __restrict__ qlr, u16* __restrict__ qhi, u16* __restrict__ qli,
    u16* __restrict__ khr, u16* __restrict__ klr, u16* __restrict__ khi, u16* __restrict__ kli,
    u16* __restrict__ vhr, u16* __restrict__ vlr, u16* __restrict__ vhi, u16* __restrict__ vli,
    const float* __restrict__ ent, AllKeys keys) {
  const uint32_t e = blockIdx.x * 256u + threadIdx.x;
  const int j = (int)blockIdx.y;
  u16 *rh, *rl, *ih, *il;
  if (j == 0) { rh = qhr; rl = qlr; ih = qhi; il = qli; }
  else if (j == 1) { rh = khr; rl = klr; ih = khi; il = kli; }
  else { rh = vhr; rl = vlr; ih = vhi; il = vli; }
  const KeySet& ks = keys.t[j];
  const uint32_t b_phase = draw_bits(ks.k[0][0], ks.k[0][1], e);
  const uint32_t b_amp   = draw_bits(ks.k[1][0], ks.k[1][1], e);
  const uint32_t b_nr    = draw_bits(ks.k[2][0], ks.k[2][1], e);
  const uint32_t b_ni    = draw_bits(ks.k[3][0], ks.k[3][1], e);
  const uint32_t b_meas  = draw_bits(ks.k[4][0], ks.k[4][1], e);
  const float flip = (unif01(b_phase) < P_NOISE) ? -1.0f : 1.0f;
  const float amp  = (unif01(b_amp)  < P_NOISE) ? 1.0f : 0.0f;
  const float keep = (unif01(b_meas) < P_NOISE * 0.5f) ? 0.0f : 1.0f;
  const float nr = normal_from_bits(b_nr);
  const float ni = normal_from_bits(b_ni);
  float r  = bf2f(rh[e]) + bf2f(rl[e]);
  float iv = bf2f(ih[e]) + bf2f(il[e]);
  r  = (r  * flip + nr * S_NOISE * amp) * keep;
  iv = (iv * flip + ni * S_NOISE * amp) * keep;
  if (j != 2) {
    const int h = ((int)e & (Dsz - 1)) >> 6;
    const float d = ent[h * Hn + h];
    r *= d; iv *= d;
  }
  uint32_t hr = bf16_rn(r);  rh[e] = (u16)hr; rl[e] = (u16)bf16_rn(r - bf2f(hr));
  uint32_t hi2 = bf16_rn(iv); ih[e] = (u16)hi2; il[e] = (u16)bf16_rn(iv - bf2f(hi2));
}

// ---------------- scores: raw S + per-block row partial (max, sumexp) --------
__global__ __launch_bounds__(256, 2) void scores_kernel(
    const u16* __restrict__ qhr, const u16* __restrict__ qlr,
    const u16* __restrict__ qhi, const u16* __restrict__ qli,
    const u16* __restrict__ khr, const u16* __restrict__ klr,
    const u16* __restrict__ khi, const u16* __restrict__ kli,
    const int* __restrict__ mask, float* __restrict__ attn,
    float2* __restrict__ part) {
  const int bh = (int)blockIdx.z;
  const int b = bh >> 4, h = bh & 15;
  const int n0 = blockIdx.x * 128, m0 = blockIdx.y * 128;
  __shared__ u16 Ahs[2][4096], Als[2][4096], Bhs[2][4096], Bls[2][4096];
  __shared__ float2 pstat[2][128];
  const int tid = (int)threadIdx.x, w = tid >> 6, l = tid & 63;
  const int wm = w >> 1, wn = w & 1;
  const int qA = (l ^ (l >> 4)) & 15, colA = (l >> 4) * 8;
  const int pr = (l ^ (l >> 4)) & 63;
  const int t0 = w * 2, t1 = w * 2 + 1;

  const size_t aoff = ((size_t)(b * Lsz) + m0 + qA) * Dsz + h * HDsz + colA;
  const size_t boff = ((size_t)(b * Lsz) + n0 + qA) * Dsz + h * HDsz + colA;

  floatx4 acc[4][4];
#pragma unroll
  for (int i = 0; i < 4; ++i)
#pragma unroll
    for (int j = 0; j < 4; ++j) acc[i][j] = (floatx4){0.f, 0.f, 0.f, 0.f};

#define STGS(bufi, AH, AL, BH, BL, K0V) { \
    const size_t g0 = (size_t)(t0 * 16) * Dsz + (K0V); \
    const size_t g1 = (size_t)(t1 * 16) * Dsz + (K0V); \
    gload16(AH + aoff + g0, &Ahs[bufi][t0 * 512]); gload16(AH + aoff + g1, &Ahs[bufi][t1 * 512]); \
    gload16(AL + aoff + g0, &Als[bufi][t0 * 512]); gload16(AL + aoff + g1, &Als[bufi][t1 * 512]); \
    gload16(BH + boff + g0, &Bhs[bufi][t0 * 512]); gload16(BH + boff + g1, &Bhs[bufi][t1 * 512]); \
    gload16(BL + boff + g0, &Bls[bufi][t0 * 512]); gload16(BL + boff + g1, &Bls[bufi][t1 * 512]); }

  STGS(0, qhr, qlr, khr, klr, 0)
  __syncthreads();
  STGS(1, qhr, qlr, khr, klr, 32)
  mfma_step(Ahs[0], Als[0], Bhs[0], Bls[0], pr, wm, wn, acc);
  __syncthreads();
  STGS(0, qhi, qli, khi, kli, 0)
  mfma_step(Ahs[1], Als[1], Bhs[1], Bls[1], pr, wm, wn, acc);
  __syncthreads();
  STGS(1, qhi, qli, khi, kli, 32)
  mfma_step(Ahs[0], Als[0], Bhs[0], Bls[0], pr, wm, wn, acc);
  __syncthreads();
  mfma_step(Ahs[1], Als[1], Bhs[1], Bls[1], pr, wm, wn, acc);
#undef STGS

  const int colLane = l & 15, rquad = l >> 4;
  int mv4[4];
#pragma unroll
  for (int nt = 0; nt < 4; ++nt)
    mv4[nt] = mask[b * Lsz + n0 + wn * 64 + nt * 16 + colLane];

  float sm[4][4], ss[4][4];   // per-(mt,j) running stats over this lane's 4 cols
#pragma unroll
  for (int mt = 0; mt < 4; ++mt) {
    const int r0 = m0 + wm * 64 + mt * 16 + rquad * 4;
#pragma unroll
    for (int j = 0; j < 4; ++j) {
      float v4[4];
#pragma unroll
      for (int nt = 0; nt < 4; ++nt) {
        const int col = n0 + wn * 64 + nt * 16 + colLane;
        float v = (mv4[nt] == 0) ? -1e9f : acc[mt][nt][j] * SCALE;
        attn[((size_t)bh * Lsz + r0 + j) * Lsz + col] = v;
        v4[nt] = v;
      }
      float m4 = fmaxf(fmaxf(v4[0], v4[1]), fmaxf(v4[2], v4[3]));
      float s4 = expf(v4[0] - m4) + expf(v4[1] - m4) + expf(v4[2] - m4) + expf(v4[3] - m4);
      sm[mt][j] = m4; ss[mt][j] = s4;
    }
  }
  // butterfly across the 16 colLane lanes
#pragma unroll
  for (int d = 1; d < 16; d <<= 1) {
#pragma unroll
    for (int mt = 0; mt < 4; ++mt)
#pragma unroll
      for (int j = 0; j < 4; ++j) {
        float om = __shfl_xor(sm[mt][j], d);
        float os = __shfl_xor(ss[mt][j], d);
        float mn = fmaxf(sm[mt][j], om);
        ss[mt][j] = ss[mt][j] * expf(sm[mt][j] - mn) + os * expf(om - mn);
        sm[mt][j] = mn;
      }
  }
  if (colLane == 0) {
#pragma unroll
    for (int mt = 0; mt < 4; ++mt)
#pragma unroll
      for (int j = 0; j < 4; ++j)
        pstat[wn][wm * 64 + mt * 16 + rquad * 4 + j] = make_float2(sm[mt][j], ss[mt][j]);
  }
  __syncthreads();
  if (tid < 128) {
    float2 a = pstat[0][tid], c = pstat[1][tid];
    float mn = fmaxf(a.x, c.x);
    float s = a.y * expf(a.x - mn) + c.y * expf(c.x - mn);
    part[((size_t)bh * Lsz + m0 + tid) * 8 + blockIdx.x] = make_float2(mn, s);
  }
}

// ---------------- combine 8 partials per row -> rowm, rowsum -----------------
__global__ __launch_bounds__(256) void rowstat2_kernel(const float2* __restrict__ part,
                                                       float* __restrict__ rowm,
                                                       float* __restrict__ rowsum) {
  const size_t row = (size_t)blockIdx.x * 256 + threadIdx.x;
  float2 p[8];
#pragma unroll
  for (int i = 0; i < 8; ++i) p[i] = part[row * 8 + i];
  float m = p[0].x;
#pragma unroll
  for (int i = 1; i < 8; ++i) m = fmaxf(m, p[i].x);
  float s = 0.f;
#pragma unroll
  for (int i = 0; i < 8; ++i) s += p[i].y * expf(p[i].x - m);
  rowm[row] = m; rowsum[row] = s;
}

// ---------------- V transpose: split [b][k][d] -> Vt [bh][n(128)][k] ---------
__global__ __launch_bounds__(256) void vtrans_kernel(
    const u16* __restrict__ vhr, const u16* __restrict__ vlr,
    const u16* __restrict__ vhi, const u16* __restrict__ vli,
    u16* __restrict__ vth, u16* __restrict__ vtl) {
  const int bh = (int)blockIdx.y;
  const int b = bh >> 4, h = bh & 15;
  const int k0 = blockIdx.x * 64;
  __shared__ uint32_t T[128 * 65];
  const int t = (int)threadIdx.x;
  const int krow = t >> 4, d4 = (t & 15) * 4;

#pragma unroll
  for (int src = 0; src < 2; ++src) {
    const u16* VH = src ? vhi : vhr;
    const u16* VL = src ? vli : vlr;
    const int nb = src * 64;
#pragma unroll
    for (int p = 0; p < 4; ++p) {
      const int k = p * 16 + krow;
      const size_t off = ((size_t)(b * Lsz) + k0 + k) * Dsz + h * HDsz + d4;
      u64 hv = *(const u64*)(VH + off);
      u64 lv = *(const u64*)(VL + off);
#pragma unroll
      for (int e = 0; e < 4; ++e) {
        uint32_t hi = (uint32_t)((hv >> (16 * e)) & 0xFFFFu);
        uint32_t lo = (uint32_t)((lv >> (16 * e)) & 0xFFFFu);
        T[(nb + d4 + e) * 65 + k] = lo | (hi << 16);
      }
    }
  }
  __syncthreads();
  const int n = t >> 1, hf = t & 1;
  const size_t rowb = ((size_t)bh * 128 + n) * Lsz + k0 + hf * 32;
#pragma unroll
  for (int g = 0; g < 4; ++g) {
    uint32_t wv[8];
#pragma unroll
    for (int u = 0; u < 8; ++u) wv[u] = T[n * 65 + hf * 32 + g * 8 + u];
    uint4v hvv, lvv;
    hvv.x = (wv[0] >> 16) | (wv[1] & 0xFFFF0000u);
    hvv.y = (wv[2] >> 16) | (wv[3] & 0xFFFF0000u);
    hvv.z = (wv[4] >> 16) | (wv[5] & 0xFFFF0000u);
    hvv.w = (wv[6] >> 16) | (wv[7] & 0xFFFF0000u);
    lvv.x = (wv[0] & 0xFFFFu) | (wv[1] << 16);
    lvv.y = (wv[2] & 0xFFFFu) | (wv[3] << 16);
    lvv.z = (wv[4] & 0xFFFFu) | (wv[5] << 16);
    lvv.w = (wv[6] & 0xFFFFu) | (wv[7] << 16);
    *(uint4v*)&vth[rowb + g * 8] = hvv;
    *(uint4v*)&vtl[rowb + g * 8] = lvv;
  }
}

// ---------------- PV: normalize attn in place + O = P @ Vt^T (split out) -----
__global__ __launch_bounds__(256, 2) void pv_kernel(
    float* __restrict__ attn, const u16* __restrict__ vth, const u16* __restrict__ vtl,
    const float* __restrict__ rowm, const float* __restrict__ rowsum,
    u16* __restrict__ ohr, u16* __restrict__ olr,
    u16* __restrict__ ohi, u16* __restrict__ oli) {
  const int bh = (int)blockIdx.y;
  const int b = bh >> 4, h = bh & 15;
  const int m0 = blockIdx.x * 128;
  __shared__ u16 Ahs[2][4096], Als[2][4096], Bhs[2][4096], Bls[2][4096];
  const int tid = (int)threadIdx.x, w = tid >> 6, l = tid & 63;
  const int wm = w >> 1, wn = w & 1;
  const int qA = (l ^ (l >> 4)) & 15, colA = (l >> 4) * 8;
  const int pr = (l ^ (l >> 4)) & 63;
  const int t0 = w * 2, t1 = w * 2 + 1;

  const int ar = tid >> 3, akq = tid & 7;
  const int am2 = akq >> 1, ahalf = akq & 1;
  int aidx[4];
  float rmv[4], inv[4];
#pragma unroll
  for (int rr = 0; rr < 4; ++rr) {
    const int trow = ar + rr * 32;
    const int p = ((trow & 15) + 16 * am2) ^ am2;
    aidx[rr] = ((trow >> 4) * 64 + p) * 8 + ahalf * 4;
    const size_t grow = (size_t)bh * Lsz + m0 + trow;
    rmv[rr] = rowm[grow]; inv[rr] = 1.0f / rowsum[grow];
  }
  float* arp = attn + ((size_t)bh * Lsz + m0 + ar) * Lsz + akq * 4;
  const u16* bhp = vth + ((size_t)bh * 128 + qA) * Lsz + colA;
  const u16* blp = vtl + ((size_t)bh * 128 + qA) * Lsz + colA;

  floatx4 acc[4][4];
#pragma unroll
  for (int i = 0; i < 4; ++i)
#pragma unroll
    for (int j = 0; j < 4; ++j) acc[i][j] = (floatx4){0.f, 0.f, 0.f, 0.f};

#define STGB(bufi, K0V) { \
    const size_t g0 = (size_t)(t0 * 16) * Lsz + (K0V); \
    const size_t g1 = (size_t)(t1 * 16) * Lsz + (K0V); \
    gload16(bhp + g0, &Bhs[bufi][t0 * 512]); gload16(bhp + g1, &Bhs[bufi][t1 * 512]); \
    gload16(blp + g0, &Bls[bufi][t0 * 512]); gload16(blp + g1, &Bls[bufi][t1 * 512]); }

#define LOADA(K0V, A4) { \
    _Pragma("unroll") for (int rr = 0; rr < 4; ++rr) \
      A4[rr] = *(const float4*)(arp + (size_t)(rr * 32) * Lsz + (K0V)); }

#define PROCA(bufi, K0V, A4) { \
    _Pragma("unroll") for (int rr = 0; rr < 4; ++rr) { \
      float4 p4; \
      p4.x = expf(A4[rr].x - rmv[rr]) * inv[rr]; \
      p4.y = expf(A4[rr].y - rmv[rr]) * inv[rr]; \
      p4.z = expf(A4[rr].z - rmv[rr]) * inv[rr]; \
      p4.w = expf(A4[rr].w - rmv[rr]) * inv[rr]; \
      *(float4*)(arp + (size_t)(rr * 32) * Lsz + (K0V)) = p4; \
      u64 h64, l64; cvt_split(p4, h64, l64); \
      *(u64*)&Ahs[bufi][aidx[rr]] = h64; *(u64*)&Als[bufi][aidx[rr]] = l64; } }

  {
    float4 a4[4];
    LOADA(0, a4)
    STGB(0, 0)
    PROCA(0, 0, a4)
  }
  __syncthreads();
  for (int kt = 0; kt < 32; kt += 2) {
    float4 n4[4];
    if (kt + 1 < 32) { LOADA((size_t)(kt + 1) * 32, n4) STGB(1, (size_t)(kt + 1) * 32) }
    mfma_step(Ahs[0], Als[0], Bhs[0], Bls[0], pr, wm, wn, acc);
    if (kt + 1 < 32) PROCA(1, (size_t)(kt + 1) * 32, n4)
    __syncthreads();
    if (kt + 2 < 32) { LOADA((size_t)(kt + 2) * 32, n4) STGB(0, (size_t)(kt + 2) * 32) }
    mfma_step(Ahs[1], Als[1], Bhs[1], Bls[1], pr, wm, wn, acc);
    if (kt + 2 < 32) PROCA(0, (size_t)(kt + 2) * 32, n4)
    __syncthreads();
  }
#undef STGB
#undef LOADA
#undef PROCA

  const int colLane = l & 15, rquad = l >> 4;
#pragma unroll
  for (int nt = 0; nt < 4; ++nt) {
    const int col = wn * 64 + nt * 16 + colLane;
    u16* oh = (col < 64) ? ohr : ohi;
    u16* ol = (col < 64) ? olr : oli;
    const int dcol = col & 63;
#pragma unroll
    for (int mt = 0; mt < 4; ++mt) {
      const int r0 = m0 + wm * 64 + mt * 16 + rquad * 4;
#pragma unroll
      for (int j = 0; j < 4; ++j) {
        float v = acc[mt][nt][j];
        const uint32_t hi = bf16_rn(v);
        const uint32_t lo = bf16_rn(v - bf2f(hi));
        const size_t oidx = ((size_t)(b * Lsz) + r0 + j) * Dsz + h * HDsz + dcol;
        oh[oidx] = (u16)hi; ol[oidx] = (u16)lo;
      }
    }
  }
}

extern "C" void kernel_launch(void* const* d_in, const int* in_sizes, int n_in,
                              void* d_out, int out_size, void* d_ws, size_t ws_size,
                              hipStream_t stream) {
  const float* x_real = (const float*)d_in[0];
  const float* x_imag = (const float*)d_in[1];
  const int*   mask   = (const int*)d_in[2];
  const float* pw[6] = {(const float*)d_in[3], (const float*)d_in[5], (const float*)d_in[7],
                        (const float*)d_in[9], (const float*)d_in[11], (const float*)d_in[13]};
  const float* pb[6] = {(const float*)d_in[4], (const float*)d_in[6], (const float*)d_in[8],
                        (const float*)d_in[10], (const float*)d_in[12], (const float*)d_in[14]};
  const float* or_w = (const float*)d_in[15]; const float* or_b = (const float*)d_in[16];
  const float* oi_w = (const float*)d_in[17]; const float* oi_b = (const float*)d_in[18];
  const float* ent  = (const float*)d_in[19];

  float* out_real = (float*)d_out;
  float* out_imag = out_real + ELEMS;
  float* attn     = out_imag + ELEMS;

  if (ws_size < 96 * MBy) return;
  uint8_t* wsb = (uint8_t*)d_ws;
  u16* qhr = (u16*)(wsb + 0 * MBy);  u16* qlr = (u16*)(wsb + 8 * MBy);
  u16* qhi = (u16*)(wsb + 16 * MBy); u16* qli = (u16*)(wsb + 24 * MBy);
  u16* khr = (u16*)(wsb + 32 * MBy); u16* klr = (u16*)(wsb + 40 * MBy);
  u16* khi = (u16*)(wsb + 48 * MBy); u16* kli = (u16*)(wsb + 56 * MBy);
  u16* xhr = (u16*)(wsb + 64 * MBy); u16* xlr = (u16*)(wsb + 72 * MBy);
  u16* xhi = (u16*)(wsb + 80 * MBy); u16* xli = (u16*)(wsb + 88 * MBy);
  u16* vth = (u16*)(wsb + 64 * MBy); u16* vtl = (u16*)(wsb + 80 * MBy);  // after proj (x dead)
  u16* ohr = (u16*)(wsb + 0 * MBy);  u16* olr = (u16*)(wsb + 8 * MBy);   // after scores (q dead)
  u16* ohi = (u16*)(wsb + 16 * MBy); u16* oli = (u16*)(wsb + 24 * MBy);
  u16* owh[2] = {(u16*)(wsb + 32 * MBy), (u16*)(wsb + 36 * MBy)};        // after scores (k dead)
  u16* owl[2] = {(u16*)(wsb + 34 * MBy), (u16*)(wsb + 38 * MBy)};

  uint8_t* atb = (uint8_t*)attn;     // attn region scratch until scores runs
  u16* vhr = (u16*)(atb + 0 * MBy);  u16* vlr = (u16*)(atb + 8 * MBy);
  u16* vhi = (u16*)(atb + 16 * MBy); u16* vli = (u16*)(atb + 24 * MBy);

  float* rowm = out_real;                       // out_real region scratch until outproj
  float* rowsum = out_real + 65536;
  float2* part = (float2*)(out_real + 131072);  // 65536 rows x 8 tiles x float2 = 4 MB

  AllKeys keys;
  for (int j = 0; j < 3; ++j) {
    uint32_t a, b2;
    tf2x32(0u, 1u, 0u, (uint32_t)j, a, b2);
#if PARTITIONABLE
    for (int i = 0; i < 5; ++i)
      tf2x32(a, b2, 0u, (uint32_t)i, keys.t[j].k[i][0], keys.t[j].k[i][1]);
#else
    uint32_t out10[10];
    for (int i = 0; i < 5; ++i) {
      uint32_t o0, o1; tf2x32(a, b2, (uint32_t)i, (uint32_t)(i + 5), o0, o1);
      out10[i] = o0; out10[i + 5] = o1;
    }
    for (int i = 0; i < 5; ++i) { keys.t[j].k[i][0] = out10[2*i]; keys.t[j].k[i][1] = out10[2*i+1]; }
#endif
  }

  // 1) split x (2x) and the 6 projection weights — one batched launch
  u16* pwh[6]; u16* pwl[6];
  for (int z = 0; z < 6; ++z) {
    pwh[z] = (u16*)(atb + 32 * MBy + (size_t)z * 4 * MBy);
    pwl[z] = pwh[z] + (size_t)Dsz * Dsz;
  }
  SJobs sj{};
  sj.j[0] = {x_real, xhr, xlr, (int)(ELEMS / 4)};
  sj.j[1] = {x_imag, xhi, xli, (int)(ELEMS / 4)};
  for (int z = 0; z < 6; ++z) sj.j[2 + z] = {pw[z], pwh[z], pwl[z], Dsz * Dsz / 4};
  split8_kernel<<<dim3(4096, 8), 256, 0, stream>>>(sj);

  // 2) projection GEMMs -> split-bf16 q/k/v (dbuf BK=32)
  GJobs pj{};
  u16* yh[6] = {qhr, qhi, khr, khi, vhr, vhi};
  u16* yl[6] = {qlr, qli, klr, kli, vlr, vli};
  const u16* ah6[6] = {xhr, xhi, xhr, xhi, xhr, xhi};
  const u16* al6[6] = {xlr, xli, xlr, xli, xlr, xli};
  for (int z = 0; z < 6; ++z) {
    pj.j[z].Ah = ah6[z]; pj.j[z].Al = al6[z];
    pj.j[z].Wh = pwh[z]; pj.j[z].Wl = pwl[z];
    pj.j[z].bias = pb[z]; pj.j[z].Yf = nullptr; pj.j[z].Yh = yh[z]; pj.j[z].Yl = yl[z];
  }
  gemm_kernel<0><<<dim3(8, 32, 6), 256, 0, stream>>>(pj);

  // 3) noise + diag(ent), in place on split arrays
  noise_kernel<<<dim3((uint32_t)(ELEMS / 256), 3), 256, 0, stream>>>(
      qhr, qlr, qhi, qli, khr, klr, khi, kli, vhr, vlr, vhi, vli, ent, keys);

  // 4) V transpose (reads noisy v splits from attn scratch)
  vtrans_kernel<<<dim3(16, 64), 256, 0, stream>>>(vhr, vlr, vhi, vli, vth, vtl);

  // 5) raw scores into attn + per-block row partials
  scores_kernel<<<dim3(8, 8, 64), 256, 0, stream>>>(
      qhr, qlr, qhi, qli, khr, klr, khi, kli, mask, attn, part);

  // 6) split output-proj weights into dead k region (batched)
  SJobs so{};
  so.j[0] = {or_w, owh[0], owl[0], Dsz * Dsz / 4};
  so.j[1] = {oi_w, owh[1], owl[1], Dsz * Dsz / 4};
  split8_kernel<<<dim3(1024, 2), 256, 0, stream>>>(so);

  // 7) combine partials -> rowm/rowsum (4 MB read instead of 268 MB)
  rowstat2_kernel<<<dim3(256), 256, 0, stream>>>(part, rowm, rowsum);

  // 8) PV: normalizes attn in place + split-bf16 attention output
  pv_kernel<<<dim3(8, 64), 256, 0, stream>>>(attn, vth, vtl, rowm, rowsum,
                                             ohr, olr, ohi, oli);

  // 9) output projections (all-gload, f32 out, dbuf BK=32)
  GJobs oj{};
  oj.j[0].Ah = ohr; oj.j[0].Al = olr; oj.j[0].Wh = owh[0]; oj.j[0].Wl = owl[0];
  oj.j[0].bias = or_b; oj.j[0].Yf = out_real;
  oj.j[1].Ah = ohi; oj.j[1].Al = oli; oj.j[1].Wh = owh[1]; oj.j[1].Wl = owl[1];
  oj.j[1].bias = oi_b; oj.j[1].Yf = out_imag;
  gemm_kernel<1><<<dim3(8, 32, 2), 256, 0, stream>>>(oj);
}

// Round 10
// 771.642 us; speedup vs baseline: 1.1079x; 1.1079x over previous
//
#include <hip/hip_runtime.h>
#include <cstdint>

#define PARTITIONABLE 1

static constexpr int Bsz = 4, Lsz = 1024, Dsz = 1024, Hn = 16, HDsz = 64;
static constexpr size_t ELEMS = (size_t)Bsz * Lsz * Dsz;     // 4194304
static constexpr uint32_t HALF_N = (uint32_t)(ELEMS / 2);
static constexpr float SCALE = 0.125f;
static constexpr float P_NOISE = 0.05f;
static constexpr float S_NOISE = 0.1f;
static constexpr size_t MBy = 1024 * 1024;

typedef unsigned short u16;
typedef uint64_t u64;
typedef __attribute__((ext_vector_type(8))) short short8v;
typedef __attribute__((ext_vector_type(4))) float floatx4;
typedef __attribute__((ext_vector_type(4))) unsigned int uint4v;

// ---- async global->LDS, 16B per lane. LDS dest wave-uniform base + lane*16.
__device__ __forceinline__ void gload16(const u16* g, u16* l) {
  __builtin_amdgcn_global_load_lds(
      (const __attribute__((address_space(1))) void*)(g),
      (__attribute__((address_space(3))) void*)(l), 16, 0, 0);
}

// ---------------- threefry2x32 (exact JAX semantics) ----------------
__host__ __device__ __forceinline__ void tf2x32(uint32_t k0, uint32_t k1,
                                                uint32_t x0, uint32_t x1,
                                                uint32_t& o0, uint32_t& o1) {
  uint32_t ks2 = k0 ^ k1 ^ 0x1BD11BDAu;
  x0 += k0; x1 += k1;
#define TFR(r) { x0 += x1; x1 = (x1 << (r)) | (x1 >> (32 - (r))); x1 ^= x0; }
  TFR(13) TFR(15) TFR(26) TFR(6)
  x0 += k1; x1 += ks2 + 1u;
  TFR(17) TFR(29) TFR(16) TFR(24)
  x0 += ks2; x1 += k0 + 2u;
  TFR(13) TFR(15) TFR(26) TFR(6)
  x0 += k0; x1 += k1 + 3u;
  TFR(17) TFR(29) TFR(16) TFR(24)
  x0 += k1; x1 += ks2 + 4u;
  TFR(13) TFR(15) TFR(26) TFR(6)
  x0 += ks2; x1 += k0 + 5u;
#undef TFR
  o0 = x0; o1 = x1;
}

struct KeySet { uint32_t k[5][2]; };
struct AllKeys { KeySet t[3]; };

__device__ __forceinline__ uint32_t draw_bits(uint32_t k0, uint32_t k1, uint32_t idx) {
#if PARTITIONABLE
  uint32_t o0, o1; tf2x32(k0, k1, 0u, idx, o0, o1);
  return o0 ^ o1;
#else
  uint32_t o0, o1;
  if (idx < HALF_N) { tf2x32(k0, k1, idx, idx + HALF_N, o0, o1); return o0; }
  tf2x32(k0, k1, idx - HALF_N, idx, o0, o1); return o1;
#endif
}

__device__ __forceinline__ float unif01(uint32_t bits) {
  return __uint_as_float((bits >> 9) | 0x3f800000u) - 1.0f;
}

__device__ __forceinline__ float normal_from_bits(uint32_t bits) {
  const float LO = -0.99999994f;
  float f = unif01(bits);
  float x = fmaxf(LO, f * 2.0f + LO);
  float w = -log1pf(-x * x);
  float p;
  if (w < 5.0f) {
    w = w - 2.5f;
    p = 2.81022636e-08f;
    p = fmaf(p, w, 3.43273939e-07f);
    p = fmaf(p, w, -3.5233877e-06f);
    p = fmaf(p, w, -4.39150654e-06f);
    p = fmaf(p, w, 0.00021858087f);
    p = fmaf(p, w, -0.00125372503f);
    p = fmaf(p, w, -0.00417768164f);
    p = fmaf(p, w, 0.246640727f);
    p = fmaf(p, w, 1.50140941f);
  } else {
    w = sqrtf(w) - 3.0f;
    p = -0.000200214257f;
    p = fmaf(p, w, 0.000100950558f);
    p = fmaf(p, w, 0.00134934322f);
    p = fmaf(p, w, -0.00367342844f);
    p = fmaf(p, w, 0.00573950773f);
    p = fmaf(p, w, -0.0076224613f);
    p = fmaf(p, w, 0.00943887047f);
    p = fmaf(p, w, 1.00167406f);
    p = fmaf(p, w, 2.83297682f);
  }
  return 1.41421356f * (p * x);
}

// ---------------- f32 -> (hi,lo) bf16 split ----------------
__device__ __forceinline__ uint32_t bf16_rn(float f) {
  uint32_t u = __float_as_uint(f);
  return (u + 0x7FFFu + ((u >> 16) & 1u)) >> 16;
}
__device__ __forceinline__ float bf2f(uint32_t h) { return __uint_as_float(h << 16); }
__device__ __forceinline__ void cvt_split(float4 v, u64& hi, u64& lo) {
  uint32_t h0 = bf16_rn(v.x), h1 = bf16_rn(v.y), h2 = bf16_rn(v.z), h3 = bf16_rn(v.w);
  float r0 = v.x - bf2f(h0), r1 = v.y - bf2f(h1), r2 = v.z - bf2f(h2), r3 = v.w - bf2f(h3);
  uint32_t l0 = bf16_rn(r0), l1 = bf16_rn(r1), l2 = bf16_rn(r2), l3 = bf16_rn(r3);
  hi = (u64)h0 | ((u64)h1 << 16) | ((u64)h2 << 32) | ((u64)h3 << 48);
  lo = (u64)l0 | ((u64)l1 << 16) | ((u64)l2 << 32) | ((u64)l3 << 48);
}

// ---------------- BK=64 MFMA tile (two K32 chunks) on fragment-packed LDS ----
__device__ __forceinline__ void mfma_tile(const u16* Ahs, const u16* Als,
                                          const u16* Bhs, const u16* Bls,
                                          int l, int wm, int wn, floatx4 acc[4][4]) {
#pragma unroll
  for (int c = 0; c < 2; ++c) {
    const int pr = (l ^ (l >> 4) ^ (c << 2)) & 63;
    short8v aH[4], aL[4], bH[4], bL[4];
#pragma unroll
    for (int t = 0; t < 4; ++t) {
      const int ia = ((c * 8 + wm * 4 + t) * 64 + pr) * 8;
      aH[t] = *(const short8v*)&Ahs[ia]; aL[t] = *(const short8v*)&Als[ia];
      const int ib = ((c * 8 + wn * 4 + t) * 64 + pr) * 8;
      bH[t] = *(const short8v*)&Bhs[ib]; bL[t] = *(const short8v*)&Bls[ib];
    }
#pragma unroll
    for (int mt = 0; mt < 4; ++mt)
#pragma unroll
      for (int nt = 0; nt < 4; ++nt) {
        acc[mt][nt] = __builtin_amdgcn_mfma_f32_16x16x32_bf16(aH[mt], bH[nt], acc[mt][nt], 0, 0, 0);
        acc[mt][nt] = __builtin_amdgcn_mfma_f32_16x16x32_bf16(aH[mt], bL[nt], acc[mt][nt], 0, 0, 0);
        acc[mt][nt] = __builtin_amdgcn_mfma_f32_16x16x32_bf16(aL[mt], bH[nt], acc[mt][nt], 0, 0, 0);
      }
  }
}

// ---------------- BK=32 MFMA step (single chunk) -----------------------------
__device__ __forceinline__ void mfma_step(const u16* Ahs, const u16* Als,
                                          const u16* Bhs, const u16* Bls,
                                          int pr, int wm, int wn, floatx4 acc[4][4]) {
  short8v aH[4], aL[4], bH[4], bL[4];
#pragma unroll
  for (int t = 0; t < 4; ++t) {
    const int ia = ((wm * 4 + t) * 64 + pr) * 8;
    aH[t] = *(const short8v*)&Ahs[ia]; aL[t] = *(const short8v*)&Als[ia];
    const int ib = ((wn * 4 + t) * 64 + pr) * 8;
    bH[t] = *(const short8v*)&Bhs[ib]; bL[t] = *(const short8v*)&Bls[ib];
  }
#pragma unroll
  for (int mt = 0; mt < 4; ++mt)
#pragma unroll
    for (int nt = 0; nt < 4; ++nt) {
      acc[mt][nt] = __builtin_amdgcn_mfma_f32_16x16x32_bf16(aH[mt], bH[nt], acc[mt][nt], 0, 0, 0);
      acc[mt][nt] = __builtin_amdgcn_mfma_f32_16x16x32_bf16(aH[mt], bL[nt], acc[mt][nt], 0, 0, 0);
      acc[mt][nt] = __builtin_amdgcn_mfma_f32_16x16x32_bf16(aL[mt], bH[nt], acc[mt][nt], 0, 0, 0);
    }
}

// ---------------- batched elementwise splitter: f32 -> hi/lo bf16 ------------
struct SJob { const float* src; u16* dh; u16* dl; int n4; };
struct SJobs { SJob j[8]; };

__global__ __launch_bounds__(256) void split8_kernel(SJobs js) {
  const SJob J = js.j[blockIdx.y];
  int i = blockIdx.x * 256 + (int)threadIdx.x;
  if (i >= J.n4) return;
  float4 v = ((const float4*)J.src)[i];
  u64 h, l; cvt_split(v, h, l);
  ((u64*)J.dh)[i] = h; ((u64*)J.dl)[i] = l;
}

// ---------------- proj GEMM: ONE A-tile -> THREE outputs (A shared) ----------
// 128x128 tile, BK=32 single-buffer, 64 KB LDS (A 16K + 3xW 48K), 2 blocks/CU.
struct GJob3 { const u16* Ah; const u16* Al;
               const u16* Wh[3]; const u16* Wl[3];
               const float* bias[3]; u16* Yh[3]; u16* Yl[3]; };
struct GJobs3 { GJob3 j[2]; };

__global__ __launch_bounds__(256, 2) void gemm3_kernel(GJobs3 jobs) {
  const GJob3 J = jobs.j[blockIdx.z];
  const int n0 = blockIdx.x * 128, m0 = blockIdx.y * 128;
  __shared__ u16 Ahs[4096], Als[4096];
  __shared__ u16 Bhs[3][4096], Bls[3][4096];
  const int tid = (int)threadIdx.x, w = tid >> 6, l = tid & 63;
  const int wm = w >> 1, wn = w & 1;
  const int qA = (l ^ (l >> 4)) & 15, colA = (l >> 4) * 8;
  const int pr = (l ^ (l >> 4)) & 63;
  const int t0 = w * 2, t1 = w * 2 + 1;

  const u16* ahp = J.Ah + (size_t)(m0 + qA) * Dsz + colA;
  const u16* alp = J.Al + (size_t)(m0 + qA) * Dsz + colA;
  const u16* whp0 = J.Wh[0] + (size_t)(n0 + qA) * Dsz + colA;
  const u16* wlp0 = J.Wl[0] + (size_t)(n0 + qA) * Dsz + colA;
  const u16* whp1 = J.Wh[1] + (size_t)(n0 + qA) * Dsz + colA;
  const u16* wlp1 = J.Wl[1] + (size_t)(n0 + qA) * Dsz + colA;
  const u16* whp2 = J.Wh[2] + (size_t)(n0 + qA) * Dsz + colA;
  const u16* wlp2 = J.Wl[2] + (size_t)(n0 + qA) * Dsz + colA;

  floatx4 acc[3][4][4];
#pragma unroll
  for (int z = 0; z < 3; ++z)
#pragma unroll
    for (int i = 0; i < 4; ++i)
#pragma unroll
      for (int j = 0; j < 4; ++j) acc[z][i][j] = (floatx4){0.f, 0.f, 0.f, 0.f};

  for (int kt = 0; kt < 32; ++kt) {
    const size_t g0 = (size_t)(t0 * 16) * Dsz + (size_t)kt * 32;
    const size_t g1 = (size_t)(t1 * 16) * Dsz + (size_t)kt * 32;
    __syncthreads();
    gload16(ahp + g0, &Ahs[t0 * 512]);  gload16(ahp + g1, &Ahs[t1 * 512]);
    gload16(alp + g0, &Als[t0 * 512]);  gload16(alp + g1, &Als[t1 * 512]);
    gload16(whp0 + g0, &Bhs[0][t0 * 512]); gload16(whp0 + g1, &Bhs[0][t1 * 512]);
    gload16(wlp0 + g0, &Bls[0][t0 * 512]); gload16(wlp0 + g1, &Bls[0][t1 * 512]);
    gload16(whp1 + g0, &Bhs[1][t0 * 512]); gload16(whp1 + g1, &Bhs[1][t1 * 512]);
    gload16(wlp1 + g0, &Bls[1][t0 * 512]); gload16(wlp1 + g1, &Bls[1][t1 * 512]);
    gload16(whp2 + g0, &Bhs[2][t0 * 512]); gload16(whp2 + g1, &Bhs[2][t1 * 512]);
    gload16(wlp2 + g0, &Bls[2][t0 * 512]); gload16(wlp2 + g1, &Bls[2][t1 * 512]);
    __syncthreads();

    short8v aH[4], aL[4];
#pragma unroll
    for (int t = 0; t < 4; ++t) {
      const int ia = ((wm * 4 + t) * 64 + pr) * 8;
      aH[t] = *(const short8v*)&Ahs[ia]; aL[t] = *(const short8v*)&Als[ia];
    }
#pragma unroll
    for (int z = 0; z < 3; ++z) {
#pragma unroll
      for (int nt = 0; nt < 4; ++nt) {          // stream b-frags: 8 regs live
        const int ib = ((wn * 4 + nt) * 64 + pr) * 8;
        short8v bH = *(const short8v*)&Bhs[z][ib];
        short8v bL = *(const short8v*)&Bls[z][ib];
#pragma unroll
        for (int mt = 0; mt < 4; ++mt) {
          acc[z][mt][nt] = __builtin_amdgcn_mfma_f32_16x16x32_bf16(aH[mt], bH, acc[z][mt][nt], 0, 0, 0);
          acc[z][mt][nt] = __builtin_amdgcn_mfma_f32_16x16x32_bf16(aH[mt], bL, acc[z][mt][nt], 0, 0, 0);
          acc[z][mt][nt] = __builtin_amdgcn_mfma_f32_16x16x32_bf16(aL[mt], bH, acc[z][mt][nt], 0, 0, 0);
        }
      }
    }
  }

  const int colLane = l & 15, rquad = l >> 4;
#pragma unroll
  for (int z = 0; z < 3; ++z) {
    u16* Yh = J.Yh[z]; u16* Yl = J.Yl[z];
#pragma unroll
    for (int nt = 0; nt < 4; ++nt) {
      const int col = n0 + wn * 64 + nt * 16 + colLane;
      const float bv = J.bias[z][col];
#pragma unroll
      for (int mt = 0; mt < 4; ++mt) {
        const int r0 = m0 + wm * 64 + mt * 16 + rquad * 4;
#pragma unroll
        for (int j2 = 0; j2 < 4; ++j2) {
          float v = acc[z][mt][nt][j2] + bv;
          const uint32_t hi = bf16_rn(v);
          const uint32_t lo = bf16_rn(v - bf2f(hi));
          Yh[(size_t)(r0 + j2) * Dsz + col] = (u16)hi;
          Yl[(size_t)(r0 + j2) * Dsz + col] = (u16)lo;
        }
      }
    }
  }
}

// ---------------- outproj GEMM: BK=64 single-buffer, f32 out -----------------
struct GJob { const u16* Ah; const u16* Al; const u16* Wh; const u16* Wl;
              const float* bias; float* Yf; };
struct GJobs { GJob j[2]; };

__global__ __launch_bounds__(256, 2) void gemm_f32_kernel(GJobs jobs) {
  const GJob J = jobs.j[blockIdx.z];
  const int n0 = blockIdx.x * 128, m0 = blockIdx.y * 128;
  __shared__ u16 Ahs[8192], Als[8192], Bhs[8192], Bls[8192];   // 64 KB
  const int tid = (int)threadIdx.x, w = tid >> 6, l = tid & 63;
  const int wm = w >> 1, wn = w & 1;
  const int cA = w >> 1, m2A = l >> 4;
  const int qA = (l ^ m2A ^ (cA << 2)) & 15;
  const int colA = cA * 32 + m2A * 8;
  const int tb = (w & 1) * 4;

  const u16* ahp = J.Ah + (size_t)(m0 + qA) * Dsz + colA;
  const u16* alp = J.Al + (size_t)(m0 + qA) * Dsz + colA;
  const u16* whp = J.Wh + (size_t)(n0 + qA) * Dsz + colA;
  const u16* wlp = J.Wl + (size_t)(n0 + qA) * Dsz + colA;

  floatx4 acc[4][4];
#pragma unroll
  for (int i = 0; i < 4; ++i)
#pragma unroll
    for (int j = 0; j < 4; ++j) acc[i][j] = (floatx4){0.f, 0.f, 0.f, 0.f};

  for (int k0 = 0; k0 < Dsz; k0 += 64) {
    __syncthreads();
#pragma unroll
    for (int i = 0; i < 4; ++i) {
      const size_t go = (size_t)((tb + i) * 16) * Dsz + k0;
      gload16(ahp + go, &Ahs[(w * 4 + i) * 512]);
      gload16(alp + go, &Als[(w * 4 + i) * 512]);
      gload16(whp + go, &Bhs[(w * 4 + i) * 512]);
      gload16(wlp + go, &Bls[(w * 4 + i) * 512]);
    }
    __syncthreads();
    mfma_tile(Ahs, Als, Bhs, Bls, l, wm, wn, acc);
  }

  const int colLane = l & 15, rquad = l >> 4;
#pragma unroll
  for (int nt = 0; nt < 4; ++nt) {
    const int col = n0 + wn * 64 + nt * 16 + colLane;
    const float bv = J.bias[col];
#pragma unroll
    for (int mt = 0; mt < 4; ++mt) {
      const int r0 = m0 + wm * 64 + mt * 16 + rquad * 4;
#pragma unroll
      for (int j2 = 0; j2 < 4; ++j2)
        J.Yf[(size_t)(r0 + j2) * Dsz + col] = acc[mt][nt][j2] + bv;
    }
  }
}

// ---------------- noise + diag(ent), in place on split q/k/v ----------------
__global__ __launch_bounds__(256) void noise_kernel(
    u16* __restrict__ qhr, u16* __restrict__ qlr, u16* __restrict__ qhi, u16* __restrict__ qli,
    u16* __restrict__ khr, u16* __restrict__ klr, u16* __restrict__ khi, u16* __restrict__ kli,
    u16* __restrict__ vhr, u16* __restrict__ vlr, u16* __restrict__ vhi, u16* __restrict__ vli,
    const float* __restrict__ ent, AllKeys keys) {
  const uint32_t e = blockIdx.x * 256u + threadIdx.x;
  const int j = (int)blockIdx.y;
  u16 *rh, *rl, *ih, *il;
  if (j == 0) { rh = qhr; rl = qlr; ih = qhi; il = qli; }
  else if (j == 1) { rh = khr; rl = klr; ih = khi; il = kli; }
  else { rh = vhr; rl = vlr; ih = vhi; il = vli; }
  const KeySet& ks = keys.t[j];
  const uint32_t b_phase = draw_bits(ks.k[0][0], ks.k[0][1], e);
  const uint32_t b_amp   = draw_bits(ks.k[1][0], ks.k[1][1], e);
  const uint32_t b_nr    = draw_bits(ks.k[2][0], ks.k[2][1], e);
  const uint32_t b_ni    = draw_bits(ks.k[3][0], ks.k[3][1], e);
  const uint32_t b_meas  = draw_bits(ks.k[4][0], ks.k[4][1], e);
  const float flip = (unif01(b_phase) < P_NOISE) ? -1.0f : 1.0f;
  const float amp  = (unif01(b_amp)  < P_NOISE) ? 1.0f : 0.0f;
  const float keep = (unif01(b_meas) < P_NOISE * 0.5f) ? 0.0f : 1.0f;
  const float nr = normal_from_bits(b_nr);
  const float ni = normal_from_bits(b_ni);
  float r  = bf2f(rh[e]) + bf2f(rl[e]);
  float iv = bf2f(ih[e]) + bf2f(il[e]);
  r  = (r  * flip + nr * S_NOISE * amp) * keep;
  iv = (iv * flip + ni * S_NOISE * amp) * keep;
  if (j != 2) {
    const int h = ((int)e & (Dsz - 1)) >> 6;
    const float d = ent[h * Hn + h];
    r *= d; iv *= d;
  }
  uint32_t hr = bf16_rn(r);  rh[e] = (u16)hr; rl[e] = (u16)bf16_rn(r - bf2f(hr));
  uint32_t hi2 = bf16_rn(iv); ih[e] = (u16)hi2; il[e] = (u16)bf16_rn(iv - bf2f(hi2));
}

// ---------------- scores: raw S = SCALE*(qr.kr + qi.ki), masked (dbuf BK=32) --
__global__ __launch_bounds__(256, 2) void scores_kernel(
    const u16* __restrict__ qhr, const u16* __restrict__ qlr,
    const u16* __restrict__ qhi, const u16* __restrict__ qli,
    const u16* __restrict__ khr, const u16* __restrict__ klr,
    const u16* __restrict__ khi, const u16* __restrict__ kli,
    const int* __restrict__ mask, float* __restrict__ attn) {
  const int bh = (int)blockIdx.z;
  const int b = bh >> 4, h = bh & 15;
  const int n0 = blockIdx.x * 128, m0 = blockIdx.y * 128;
  __shared__ u16 Ahs[2][4096], Als[2][4096], Bhs[2][4096], Bls[2][4096];
  const int tid = (int)threadIdx.x, w = tid >> 6, l = tid & 63;
  const int wm = w >> 1, wn = w & 1;
  const int qA = (l ^ (l >> 4)) & 15, colA = (l >> 4) * 8;
  const int pr = (l ^ (l >> 4)) & 63;
  const int t0 = w * 2, t1 = w * 2 + 1;

  const size_t aoff = ((size_t)(b * Lsz) + m0 + qA) * Dsz + h * HDsz + colA;
  const size_t boff = ((size_t)(b * Lsz) + n0 + qA) * Dsz + h * HDsz + colA;

  floatx4 acc[4][4];
#pragma unroll
  for (int i = 0; i < 4; ++i)
#pragma unroll
    for (int j = 0; j < 4; ++j) acc[i][j] = (floatx4){0.f, 0.f, 0.f, 0.f};

#define STGS(bufi, AH, AL, BH, BL, K0V) { \
    const size_t g0 = (size_t)(t0 * 16) * Dsz + (K0V); \
    const size_t g1 = (size_t)(t1 * 16) * Dsz + (K0V); \
    gload16(AH + aoff + g0, &Ahs[bufi][t0 * 512]); gload16(AH + aoff + g1, &Ahs[bufi][t1 * 512]); \
    gload16(AL + aoff + g0, &Als[bufi][t0 * 512]); gload16(AL + aoff + g1, &Als[bufi][t1 * 512]); \
    gload16(BH + boff + g0, &Bhs[bufi][t0 * 512]); gload16(BH + boff + g1, &Bhs[bufi][t1 * 512]); \
    gload16(BL + boff + g0, &Bls[bufi][t0 * 512]); gload16(BL + boff + g1, &Bls[bufi][t1 * 512]); }

  STGS(0, qhr, qlr, khr, klr, 0)
  __syncthreads();
  STGS(1, qhr, qlr, khr, klr, 32)
  mfma_step(Ahs[0], Als[0], Bhs[0], Bls[0], pr, wm, wn, acc);
  __syncthreads();
  STGS(0, qhi, qli, khi, kli, 0)
  mfma_step(Ahs[1], Als[1], Bhs[1], Bls[1], pr, wm, wn, acc);
  __syncthreads();
  STGS(1, qhi, qli, khi, kli, 32)
  mfma_step(Ahs[0], Als[0], Bhs[0], Bls[0], pr, wm, wn, acc);
  __syncthreads();
  mfma_step(Ahs[1], Als[1], Bhs[1], Bls[1], pr, wm, wn, acc);
#undef STGS

  const int colLane = l & 15, rquad = l >> 4;
#pragma unroll
  for (int nt = 0; nt < 4; ++nt) {
    const int col = n0 + wn * 64 + nt * 16 + colLane;
    const int mv = mask[b * Lsz + col];
#pragma unroll
    for (int mt = 0; mt < 4; ++mt) {
      const int r0 = m0 + wm * 64 + mt * 16 + rquad * 4;
#pragma unroll
      for (int j = 0; j < 4; ++j)
        attn[((size_t)bh * Lsz + r0 + j) * Lsz + col] =
            (mv == 0) ? -1e9f : acc[mt][nt][j] * SCALE;
    }
  }
}

// ---------------- V transpose: split [b][k][d] -> Vt [bh][n(128)][k] ---------
__global__ __launch_bounds__(256) void vtrans_kernel(
    const u16* __restrict__ vhr, const u16* __restrict__ vlr,
    const u16* __restrict__ vhi, const u16* __restrict__ vli,
    u16* __restrict__ vth, u16* __restrict__ vtl) {
  const int bh = (int)blockIdx.y;
  const int b = bh >> 4, h = bh & 15;
  const int k0 = blockIdx.x * 64;
  __shared__ uint32_t T[128 * 65];
  const int t = (int)threadIdx.x;
  const int krow = t >> 4, d4 = (t & 15) * 4;

#pragma unroll
  for (int src = 0; src < 2; ++src) {
    const u16* VH = src ? vhi : vhr;
    const u16* VL = src ? vli : vlr;
    const int nb = src * 64;
#pragma unroll
    for (int p = 0; p < 4; ++p) {
      const int k = p * 16 + krow;
      const size_t off = ((size_t)(b * Lsz) + k0 + k) * Dsz + h * HDsz + d4;
      u64 hv = *(const u64*)(VH + off);
      u64 lv = *(const u64*)(VL + off);
#pragma unroll
      for (int e = 0; e < 4; ++e) {
        uint32_t hi = (uint32_t)((hv >> (16 * e)) & 0xFFFFu);
        uint32_t lo = (uint32_t)((lv >> (16 * e)) & 0xFFFFu);
        T[(nb + d4 + e) * 65 + k] = lo | (hi << 16);
      }
    }
  }
  __syncthreads();
  const int n = t >> 1, hf = t & 1;
  const size_t rowb = ((size_t)bh * 128 + n) * Lsz + k0 + hf * 32;
#pragma unroll
  for (int g = 0; g < 4; ++g) {
    uint32_t wv[8];
#pragma unroll
    for (int u = 0; u < 8; ++u) wv[u] = T[n * 65 + hf * 32 + g * 8 + u];
    uint4v hvv, lvv;
    hvv.x = (wv[0] >> 16) | (wv[1] & 0xFFFF0000u);
    hvv.y = (wv[2] >> 16) | (wv[3] & 0xFFFF0000u);
    hvv.z = (wv[4] >> 16) | (wv[5] & 0xFFFF0000u);
    hvv.w = (wv[6] >> 16) | (wv[7] & 0xFFFF0000u);
    lvv.x = (wv[0] & 0xFFFFu) | (wv[1] << 16);
    lvv.y = (wv[2] & 0xFFFFu) | (wv[3] << 16);
    lvv.z = (wv[4] & 0xFFFFu) | (wv[5] << 16);
    lvv.w = (wv[6] & 0xFFFFu) | (wv[7] << 16);
    *(uint4v*)&vth[rowb + g * 8] = hvv;
    *(uint4v*)&vtl[rowb + g * 8] = lvv;
  }
}

// ---------------- row stats: per row of S, max and sum(exp(s-m)) -------------
__global__ __launch_bounds__(256) void rowstat_kernel(const float* __restrict__ S,
                                                      float* __restrict__ rowm,
                                                      float* __restrict__ rowsum) {
  const int wv = (int)threadIdx.x >> 6, lane = (int)threadIdx.x & 63;
  const size_t row = (size_t)blockIdx.x * 4 + wv;
  const float* p = S + row * Lsz;
  float4 v[4];
#pragma unroll
  for (int i = 0; i < 4; ++i) v[i] = *(const float4*)(p + i * 256 + lane * 4);
  float m = -3.402823466e38f;
#pragma unroll
  for (int i = 0; i < 4; ++i)
    m = fmaxf(m, fmaxf(fmaxf(v[i].x, v[i].y), fmaxf(v[i].z, v[i].w)));
#pragma unroll
  for (int d = 1; d < 64; d <<= 1) m = fmaxf(m, __shfl_xor(m, d));
  float s = 0.f;
#pragma unroll
  for (int i = 0; i < 4; ++i)
    s += expf(v[i].x - m) + expf(v[i].y - m) + expf(v[i].z - m) + expf(v[i].w - m);
#pragma unroll
  for (int d = 1; d < 64; d <<= 1) s += __shfl_xor(s, d);
  if (lane == 0) { rowm[row] = m; rowsum[row] = s; }
}

// ---------------- PV: normalize attn in place + O = P @ Vt^T (split out) -----
__global__ __launch_bounds__(256, 2) void pv_kernel(
    float* __restrict__ attn, const u16* __restrict__ vth, const u16* __restrict__ vtl,
    const float* __restrict__ rowm, const float* __restrict__ rowsum,
    u16* __restrict__ ohr, u16* __restrict__ olr,
    u16* __restrict__ ohi, u16* __restrict__ oli) {
  const int bh = (int)blockIdx.y;
  const int b = bh >> 4, h = bh & 15;
  const int m0 = blockIdx.x * 128;
  __shared__ u16 Ahs[2][4096], Als[2][4096], Bhs[2][4096], Bls[2][4096];
  const int tid = (int)threadIdx.x, w = tid >> 6, l = tid & 63;
  const int wm = w >> 1, wn = w & 1;
  const int qA = (l ^ (l >> 4)) & 15, colA = (l >> 4) * 8;
  const int pr = (l ^ (l >> 4)) & 63;
  const int t0 = w * 2, t1 = w * 2 + 1;

  const int ar = tid >> 3, akq = tid & 7;
  const int am2 = akq >> 1, ahalf = akq & 1;
  int aidx[4];
  float rmv[4], inv[4];
#pragma unroll
  for (int rr = 0; rr < 4; ++rr) {
    const int trow = ar + rr * 32;
    const int p = ((trow & 15) + 16 * am2) ^ am2;
    aidx[rr] = ((trow >> 4) * 64 + p) * 8 + ahalf * 4;
    const size_t grow = (size_t)bh * Lsz + m0 + trow;
    rmv[rr] = rowm[grow]; inv[rr] = 1.0f / rowsum[grow];
  }
  float* arp = attn + ((size_t)bh * Lsz + m0 + ar) * Lsz + akq * 4;
  const u16* bhp = vth + ((size_t)bh * 128 + qA) * Lsz + colA;
  const u16* blp = vtl + ((size_t)bh * 128 + qA) * Lsz + colA;

  floatx4 acc[4][4];
#pragma unroll
  for (int i = 0; i < 4; ++i)
#pragma unroll
    for (int j = 0; j < 4; ++j) acc[i][j] = (floatx4){0.f, 0.f, 0.f, 0.f};

#define STGB(bufi, K0V) { \
    const size_t g0 = (size_t)(t0 * 16) * Lsz + (K0V); \
    const size_t g1 = (size_t)(t1 * 16) * Lsz + (K0V); \
    gload16(bhp + g0, &Bhs[bufi][t0 * 512]); gload16(bhp + g1, &Bhs[bufi][t1 * 512]); \
    gload16(blp + g0, &Bls[bufi][t0 * 512]); gload16(blp + g1, &Bls[bufi][t1 * 512]); }

#define LOADA(K0V, A4) { \
    _Pragma("unroll") for (int rr = 0; rr < 4; ++rr) \
      A4[rr] = *(const float4*)(arp + (size_t)(rr * 32) * Lsz + (K0V)); }

#define PROCA(bufi, K0V, A4) { \
    _Pragma("unroll") for (int rr = 0; rr < 4; ++rr) { \
      float4 p4; \
      p4.x = expf(A4[rr].x - rmv[rr]) * inv[rr]; \
      p4.y = expf(A4[rr].y - rmv[rr]) * inv[rr]; \
      p4.z = expf(A4[rr].z - rmv[rr]) * inv[rr]; \
      p4.w = expf(A4[rr].w - rmv[rr]) * inv[rr]; \
      *(float4*)(arp + (size_t)(rr * 32) * Lsz + (K0V)) = p4; \
      u64 h64, l64; cvt_split(p4, h64, l64); \
      *(u64*)&Ahs[bufi][aidx[rr]] = h64; *(u64*)&Als[bufi][aidx[rr]] = l64; } }

  {
    float4 a4[4];
    LOADA(0, a4)
    STGB(0, 0)
    PROCA(0, 0, a4)
  }
  __syncthreads();
  for (int kt = 0; kt < 32; kt += 2) {
    float4 n4[4];
    if (kt + 1 < 32) { LOADA((size_t)(kt + 1) * 32, n4) STGB(1, (size_t)(kt + 1) * 32) }
    mfma_step(Ahs[0], Als[0], Bhs[0], Bls[0], pr, wm, wn, acc);
    if (kt + 1 < 32) PROCA(1, (size_t)(kt + 1) * 32, n4)
    __syncthreads();
    if (kt + 2 < 32) { LOADA((size_t)(kt + 2) * 32, n4) STGB(0, (size_t)(kt + 2) * 32) }
    mfma_step(Ahs[1], Als[1], Bhs[1], Bls[1], pr, wm, wn, acc);
    if (kt + 2 < 32) PROCA(0, (size_t)(kt + 2) * 32, n4)
    __syncthreads();
  }
#undef STGB
#undef LOADA
#undef PROCA

  const int colLane = l & 15, rquad = l >> 4;
#pragma unroll
  for (int nt = 0; nt < 4; ++nt) {
    const int col = wn * 64 + nt * 16 + colLane;
    u16* oh = (col < 64) ? ohr : ohi;
    u16* ol = (col < 64) ? olr : oli;
    const int dcol = col & 63;
#pragma unroll
    for (int mt = 0; mt < 4; ++mt) {
      const int r0 = m0 + wm * 64 + mt * 16 + rquad * 4;
#pragma unroll
      for (int j = 0; j < 4; ++j) {
        float v = acc[mt][nt][j];
        const uint32_t hi = bf16_rn(v);
        const uint32_t lo = bf16_rn(v - bf2f(hi));
        const size_t oidx = ((size_t)(b * Lsz) + r0 + j) * Dsz + h * HDsz + dcol;
        oh[oidx] = (u16)hi; ol[oidx] = (u16)lo;
      }
    }
  }
}

extern "C" void kernel_launch(void* const* d_in, const int* in_sizes, int n_in,
                              void* d_out, int out_size, void* d_ws, size_t ws_size,
                              hipStream_t stream) {
  const float* x_real = (const float*)d_in[0];
  const float* x_imag = (const float*)d_in[1];
  const int*   mask   = (const int*)d_in[2];
  const float* pw[6] = {(const float*)d_in[3], (const float*)d_in[5], (const float*)d_in[7],
                        (const float*)d_in[9], (const float*)d_in[11], (const float*)d_in[13]};
  const float* pb[6] = {(const float*)d_in[4], (const float*)d_in[6], (const float*)d_in[8],
                        (const float*)d_in[10], (const float*)d_in[12], (const float*)d_in[14]};
  const float* or_w = (const float*)d_in[15]; const float* or_b = (const float*)d_in[16];
  const float* oi_w = (const float*)d_in[17]; const float* oi_b = (const float*)d_in[18];
  const float* ent  = (const float*)d_in[19];

  float* out_real = (float*)d_out;
  float* out_imag = out_real + ELEMS;
  float* attn     = out_imag + ELEMS;

  if (ws_size < 96 * MBy) return;
  uint8_t* wsb = (uint8_t*)d_ws;
  u16* qhr = (u16*)(wsb + 0 * MBy);  u16* qlr = (u16*)(wsb + 8 * MBy);
  u16* qhi = (u16*)(wsb + 16 * MBy); u16* qli = (u16*)(wsb + 24 * MBy);
  u16* khr = (u16*)(wsb + 32 * MBy); u16* klr = (u16*)(wsb + 40 * MBy);
  u16* khi = (u16*)(wsb + 48 * MBy); u16* kli = (u16*)(wsb + 56 * MBy);
  u16* xhr = (u16*)(wsb + 64 * MBy); u16* xlr = (u16*)(wsb + 72 * MBy);
  u16* xhi = (u16*)(wsb + 80 * MBy); u16* xli = (u16*)(wsb + 88 * MBy);
  u16* vth = (u16*)(wsb + 64 * MBy); u16* vtl = (u16*)(wsb + 80 * MBy);  // after proj (x dead)
  u16* ohr = (u16*)(wsb + 0 * MBy);  u16* olr = (u16*)(wsb + 8 * MBy);   // after scores (q dead)
  u16* ohi = (u16*)(wsb + 16 * MBy); u16* oli = (u16*)(wsb + 24 * MBy);
  u16* owh[2] = {(u16*)(wsb + 32 * MBy), (u16*)(wsb + 36 * MBy)};        // after scores (k dead)
  u16* owl[2] = {(u16*)(wsb + 34 * MBy), (u16*)(wsb + 38 * MBy)};

  uint8_t* atb = (uint8_t*)attn;     // attn region scratch until scores runs
  u16* vhr = (u16*)(atb + 0 * MBy);  u16* vlr = (u16*)(atb + 8 * MBy);
  u16* vhi = (u16*)(atb + 16 * MBy); u16* vli = (u16*)(atb + 24 * MBy);

  float* rowm = out_real;            // out_real region scratch until outproj
  float* rowsum = out_real + 65536;

  AllKeys keys;
  for (int j = 0; j < 3; ++j) {
    uint32_t a, b2;
    tf2x32(0u, 1u, 0u, (uint32_t)j, a, b2);
#if PARTITIONABLE
    for (int i = 0; i < 5; ++i)
      tf2x32(a, b2, 0u, (uint32_t)i, keys.t[j].k[i][0], keys.t[j].k[i][1]);
#else
    uint32_t out10[10];
    for (int i = 0; i < 5; ++i) {
      uint32_t o0, o1; tf2x32(a, b2, (uint32_t)i, (uint32_t)(i + 5), o0, o1);
      out10[i] = o0; out10[i + 5] = o1;
    }
    for (int i = 0; i < 5; ++i) { keys.t[j].k[i][0] = out10[2*i]; keys.t[j].k[i][1] = out10[2*i+1]; }
#endif
  }

  // 1) split x (2x) and the 6 projection weights — one batched launch
  u16* pwh[6]; u16* pwl[6];
  for (int z = 0; z < 6; ++z) {
    pwh[z] = (u16*)(atb + 32 * MBy + (size_t)z * 4 * MBy);
    pwl[z] = pwh[z] + (size_t)Dsz * Dsz;
  }
  SJobs sj{};
  sj.j[0] = {x_real, xhr, xlr, (int)(ELEMS / 4)};
  sj.j[1] = {x_imag, xhi, xli, (int)(ELEMS / 4)};
  for (int z = 0; z < 6; ++z) sj.j[2 + z] = {pw[z], pwh[z], pwl[z], Dsz * Dsz / 4};
  split8_kernel<<<dim3(4096, 8), 256, 0, stream>>>(sj);

  // 2) projection GEMMs: one A-tile -> 3 outputs (A shared across q/k/v)
  // pw index map: qr=0 qi=1 kr=2 ki=3 vr=4 vi=5
  GJobs3 pj{};
  pj.j[0].Ah = xhr; pj.j[0].Al = xlr;   // real group -> {qr, kr, vr}
  pj.j[0].Wh[0] = pwh[0]; pj.j[0].Wl[0] = pwl[0]; pj.j[0].bias[0] = pb[0];
  pj.j[0].Yh[0] = qhr; pj.j[0].Yl[0] = qlr;
  pj.j[0].Wh[1] = pwh[2]; pj.j[0].Wl[1] = pwl[2]; pj.j[0].bias[1] = pb[2];
  pj.j[0].Yh[1] = khr; pj.j[0].Yl[1] = klr;
  pj.j[0].Wh[2] = pwh[4]; pj.j[0].Wl[2] = pwl[4]; pj.j[0].bias[2] = pb[4];
  pj.j[0].Yh[2] = vhr; pj.j[0].Yl[2] = vlr;
  pj.j[1].Ah = xhi; pj.j[1].Al = xli;   // imag group -> {qi, ki, vi}
  pj.j[1].Wh[0] = pwh[1]; pj.j[1].Wl[0] = pwl[1]; pj.j[1].bias[0] = pb[1];
  pj.j[1].Yh[0] = qhi; pj.j[1].Yl[0] = qli;
  pj.j[1].Wh[1] = pwh[3]; pj.j[1].Wl[1] = pwl[3]; pj.j[1].bias[1] = pb[3];
  pj.j[1].Yh[1] = khi; pj.j[1].Yl[1] = kli;
  pj.j[1].Wh[2] = pwh[5]; pj.j[1].Wl[2] = pwl[5]; pj.j[1].bias[2] = pb[5];
  pj.j[1].Yh[2] = vhi; pj.j[1].Yl[2] = vli;
  gemm3_kernel<<<dim3(8, 32, 2), 256, 0, stream>>>(pj);

  // 3) noise + diag(ent), in place on split arrays
  noise_kernel<<<dim3((uint32_t)(ELEMS / 256), 3), 256, 0, stream>>>(
      qhr, qlr, qhi, qli, khr, klr, khi, kli, vhr, vlr, vhi, vli, ent, keys);

  // 4) V transpose (reads noisy v splits from attn scratch)
  vtrans_kernel<<<dim3(16, 64), 256, 0, stream>>>(vhr, vlr, vhi, vli, vth, vtl);

  // 5) raw scores into attn (clobbers v/weight scratch in attn region)
  scores_kernel<<<dim3(8, 8, 64), 256, 0, stream>>>(
      qhr, qlr, qhi, qli, khr, klr, khi, kli, mask, attn);

  // 6) split output-proj weights into dead k region (batched)
  SJobs so{};
  so.j[0] = {or_w, owh[0], owl[0], Dsz * Dsz / 4};
  so.j[1] = {oi_w, owh[1], owl[1], Dsz * Dsz / 4};
  split8_kernel<<<dim3(1024, 2), 256, 0, stream>>>(so);

  // 7) per-row softmax stats
  rowstat_kernel<<<dim3(16384), 256, 0, stream>>>(attn, rowm, rowsum);

  // 8) PV: normalizes attn in place + split-bf16 attention output
  pv_kernel<<<dim3(8, 64), 256, 0, stream>>>(attn, vth, vtl, rowm, rowsum,
                                             ohr, olr, ohi, oli);

  // 9) output projections (all-gload, f32 out, BK=64 single-buffer)
  GJobs oj{};
  oj.j[0].Ah = ohr; oj.j[0].Al = olr; oj.j[0].Wh = owh[0]; oj.j[0].Wl = owl[0];
  oj.j[0].bias = or_b; oj.j[0].Yf = out_real;
  oj.j[1].Ah = ohi; oj.j[1].Al = oli; oj.j[1].Wh = owh[1]; oj.j[1].Wl = owl[1];
  oj.j[1].bias = oi_b; oj.j[1].Yf = out_imag;
  gemm_f32_kernel<<<dim3(8, 32, 2), 256, 0, stream>>>(oj);
}